// Round 13
// baseline (232.131 us; speedup 1.0000x reference)
//
#include <hip/hip_runtime.h>

// ---------------------------------------------------------------------------
// RefinedQuantumEntanglementLayer on MI355X (gfx950)
//
// out = (l2norm(x) @ expm(Mr-Mr^T) @ expm(Mi-Mi^T) + bias)^2 * softmax(qg)
//
// r13: chain GEMM rounds are TLP-starved (16 serial latency-gated K-steps
// at 3 blocks/CU). Tiles shrink 64x64 -> 32x64: 2-unit rounds run 1024
// blocks (4/CU, 36KB LDS, 16 waves/CU), W round 512. Same traffic, same
// per-element K order (bit-exact), double the latency-hiding TLP.
// Main GEMM: bj-fastest dispatch so the 4 blocks sharing an Xn panel are
// dispatch-adjacent (panel fetched from HBM once, re-reads L3-warm).
//
// Chain math (deg-8 Paterson-Stockmeyer, s=3):  [f(A,B) = A*B^T]
//   X2 = -f(X,X); X3 = -f(X2,X); X4 = f(X2,X2)
//   q0 = I+X+X2/2+X3/6 (f32); q1t = elementwise-transposed q1 (odd flips)
//   E  = f(X4,q1t)+q0 [dual-write -> Et]
//   squarings E' = f(E,Et) [dual -> E't]; W = U^T = f(E3t_B, E3_A)
// main (r10 pipeline): 256^2 tile BK=32 4-buf counted-vmcnt.
// ---------------------------------------------------------------------------

typedef unsigned int u32;
typedef unsigned short u16;
typedef __attribute__((ext_vector_type(8))) short short8;   // 8 x bf16 raw
typedef __attribute__((ext_vector_type(4))) float f32x4;

#define GLOBAL_AS __attribute__((address_space(1)))
#define LDS_AS    __attribute__((address_space(3)))

constexpr int D = 1024;
constexpr float EXPM_SCALE = 1.0f / 8.0f;   // s = 3 squarings

__device__ __forceinline__ u16 f2bf(float f) {
  union { float f; u32 u; } v; v.f = f;
  u32 r = (v.u + 0x7FFFu + ((v.u >> 16) & 1u)) >> 16;
  return (u16)r;
}
__device__ __forceinline__ float bf2f(u16 u) {
  union { u32 u; float f; } v; v.u = ((u32)u) << 16;
  return v.f;
}

// async global->LDS, 16B per lane; lds base must be wave-uniform.
__device__ __forceinline__ void g2l16(const void* g, void* l) {
  __builtin_amdgcn_global_load_lds((const GLOBAL_AS u32*)g, (LDS_AS u32*)l,
                                   16, 0, 0);
}

#define WAITV(N)                                                   \
  do {                                                             \
    asm volatile("s_waitcnt vmcnt(" #N ")" ::: "memory");          \
    __builtin_amdgcn_sched_barrier(0);                             \
  } while (0)

// ---------------------------------------------------------------------------
// normalize 8 rows of x -> bf16 (tail body shared by chain launches)
__device__ void norm_rows8(const float* __restrict__ x, u16* __restrict__ Xn,
                           int r0, int tid, float* sred) {
  float4 v[8];
#pragma unroll
  for (int i = 0; i < 8; ++i)
    v[i] = ((const float4*)(x + (size_t)(r0 + i) * D))[tid];
  float ss[8];
#pragma unroll
  for (int i = 0; i < 8; ++i)
    ss[i] = v[i].x * v[i].x + v[i].y * v[i].y + v[i].z * v[i].z +
            v[i].w * v[i].w;
  for (int o = 32; o; o >>= 1)
#pragma unroll
    for (int i = 0; i < 8; ++i) ss[i] += __shfl_down(ss[i], o);
  const int w = tid >> 6;
  if ((tid & 63) == 0)
#pragma unroll
    for (int i = 0; i < 8; ++i) sred[i * 4 + w] = ss[i];
  __syncthreads();
#pragma unroll
  for (int i = 0; i < 8; ++i) {
    const float tot =
        sred[i * 4 + 0] + sred[i * 4 + 1] + sred[i * 4 + 2] + sred[i * 4 + 3];
    const float inv = rsqrtf(fmaxf(tot, 1e-12f));
    ushort4 o4;
    o4.x = f2bf(v[i].x * inv); o4.y = f2bf(v[i].y * inv);
    o4.z = f2bf(v[i].z * inv); o4.w = f2bf(v[i].w * inv);
    ((ushort4*)(Xn + (size_t)(r0 + i) * D))[tid] = o4;
  }
}

// ---------------------------------------------------------------------------
// L1: skew tiles (512 jobs) + norm tail
struct SkewParams {
  const float *Mr, *Mi;
  u16 *X0, *X1;
  const float* x;
  u16* Xn;
  int row0;
};
__global__ __launch_bounds__(256) void skew_norm_kernel(SkewParams p) {
  __shared__ __align__(16) float t2[64][67];
  const int bid = blockIdx.x, tid = threadIdx.x;
  if (bid >= 512) {
    norm_rows8(p.x, p.Xn, p.row0 + (bid - 512) * 8, tid, &t2[0][0]);
    return;
  }
  const int z = bid >> 8, t = bid & 255;
  const float* M = z ? p.Mi : p.Mr;
  u16* X = z ? p.X1 : p.X0;
  const int bi = t >> 4, bj = t & 15;
  const int r0 = tid >> 4, c0 = (tid & 15) * 4;
  float4 own[4];
#pragma unroll
  for (int i = 0; i < 4; ++i) {
    const int r = i * 16 + r0;
    own[i] = *(const float4*)(M + (size_t)(bi * 64 + r) * D + bj * 64 + c0);
    const float4 tr =
        *(const float4*)(M + (size_t)(bj * 64 + r) * D + bi * 64 + c0);
    t2[r][c0 + 0] = tr.x; t2[r][c0 + 1] = tr.y;
    t2[r][c0 + 2] = tr.z; t2[r][c0 + 3] = tr.w;
  }
  __syncthreads();
#pragma unroll
  for (int i = 0; i < 4; ++i) {
    const int r = i * 16 + r0;
    const float o[4] = {own[i].x, own[i].y, own[i].z, own[i].w};
    ushort4 hv;
    u16* hp = (u16*)&hv;
#pragma unroll
    for (int j = 0; j < 4; ++j)
      hp[j] = f2bf((o[j] - t2[c0 + j][r]) * EXPM_SCALE);
    *(ushort4*)(X + (size_t)(bi * 64 + r) * D + bj * 64 + c0) = hv;
  }
}

// ---------------------------------------------------------------------------
// generic chain GEMM round + norm tail. 32x64 tile, BK=64, 4 waves
// (2x2; each wave 16x32 out), 3 LDS bufs (36KB -> 4 blocks/CU), 2-ahead
// prefetch, counted vmcnt(3), tail 3/0. 512 tiles per 1024^2 job.
struct CJob {
  const u16 *A, *B;
  const float* C;
  u16 *Dst, *DT;
  float alpha;
};
struct GNParams {
  CJob jobs[2];
  int njobs;  // nunits * 512 tile jobs
  const float* x;
  u16* Xn;
  int row0;
};
__global__ __launch_bounds__(256) void gemm_norm_kernel(GNParams p) {
  __shared__ __align__(16) u16 ldsA[3][2048];   // 32 x 64
  __shared__ __align__(16) u16 ldsB[3][4096];   // 64 x 64
  const int bid = blockIdx.x, tid = threadIdx.x;
  if (bid >= p.njobs) {
    norm_rows8(p.x, p.Xn, p.row0 + (bid - p.njobs) * 8, tid,
               (float*)&ldsB[0][0]);
    return;
  }
  const CJob jb = p.jobs[bid >> 9];
  const int t = bid & 511;
  const int bi = t >> 4, bj = t & 15;   // 32 x 16 tiles of 32x64
  const int w = tid >> 6, lane = tid & 63;
  const int wr = w >> 1, wc = w & 1;
  f32x4 acc[2];
  acc[0] = f32x4{0.f, 0.f, 0.f, 0.f};
  acc[1] = f32x4{0.f, 0.f, 0.f, 0.f};
  const int r_l = lane >> 3, c_l = lane & 7;
  const int arow = tid >> 3, ac = tid & 7;   // A-stage mapping (1 load/thr)

  auto stage = [&](int buf, int kt) {   // 3 g2l16 per thread
    const int k0 = kt * 64;
    g2l16(jb.A + (size_t)(bi * 32 + arow) * D + k0 + (ac ^ (arow & 7)) * 8,
          (char*)&ldsA[buf][0] + w * 1024);   // HW adds lane*16 -> tid*16
#pragma unroll
    for (int pp = 0; pp < 2; ++pp) {
      const int row = pp * 32 + w * 8 + r_l;
      const int chunk = c_l ^ (row & 7);  // inverse swizzle on global source
      g2l16(jb.B + (size_t)(bj * 64 + row) * D + k0 + chunk * 8,
            (char*)&ldsB[buf][0] + pp * 4096 + w * 1024);
    }
  };
  auto compute = [&](int buf) {
#pragma unroll
    for (int h = 0; h < 2; ++h) {
      const int kk = h * 32 + (lane >> 4) * 8;
      const int rowa = wr * 16 + (lane & 15);
      const int offa = rowa * 128 + ((kk * 2) ^ ((rowa & 7) << 4));
      const short8 a = *(const short8*)((const char*)&ldsA[buf][0] + offa);
      short8 b[2];
#pragma unroll
      for (int n = 0; n < 2; ++n) {
        const int row = wc * 32 + n * 16 + (lane & 15);
        const int off = row * 128 + ((kk * 2) ^ ((row & 7) << 4));
        b[n] = *(const short8*)((const char*)&ldsB[buf][0] + off);
      }
#pragma unroll
      for (int n = 0; n < 2; ++n)
        acc[n] = __builtin_amdgcn_mfma_f32_16x16x32_bf16(a, b[n], acc[n],
                                                         0, 0, 0);
    }
  };

  stage(0, 0); stage(1, 1);   // 6 loads in flight (2-ahead)
  for (int s = 0; s < 14; ++s) {
    WAITV(3);                          // own G(s) landed (G(s+1) may fly)
    __builtin_amdgcn_s_barrier();      // all threads' G(s) landed;
    __builtin_amdgcn_sched_barrier(0); //  all finished compute(s-1)
    stage((s + 2) % 3, s + 2);         // overwrites buf(s-1): reads done
    compute(s % 3);
  }
  WAITV(3);
  __builtin_amdgcn_s_barrier();
  __builtin_amdgcn_sched_barrier(0);
  compute(14 % 3);
  WAITV(0);
  __builtin_amdgcn_s_barrier();
  __builtin_amdgcn_sched_barrier(0);
  compute(15 % 3);

  const int or0 = bi * 32 + wr * 16, oc0 = bj * 64 + wc * 32;
#pragma unroll
  for (int n = 0; n < 2; ++n) {
    const int row0 = or0 + (lane >> 4) * 4;
    const int col = oc0 + n * 16 + (lane & 15);
    ushort4 dv;
    u16* dp = (u16*)&dv;
#pragma unroll
    for (int r = 0; r < 4; ++r) {
      float v = acc[n][r] * jb.alpha;
      if (jb.C) v += jb.C[(size_t)(row0 + r) * D + col];
      dp[r] = f2bf(v);
      jb.Dst[(size_t)(row0 + r) * D + col] = dp[r];
    }
    if (jb.DT)  // transposed tile: DT[col][row0..row0+3], one 8B store
      *(ushort4*)(jb.DT + (size_t)col * D + row0) = dv;
  }
}

// ---------------------------------------------------------------------------
// L3: fused X3/X4 + buildq + gate + norm tail. BK=32, 3 arrays x 3 bufs
// x 4KB = 36KB (4 blocks/CU), 2-ahead, counted vmcnt(3), tail 3/0.
struct X34Params {
  const u16 *X[2], *X2[2];
  u16 *X3[2], *X4[2], *q1t[2];
  float* q0[2];
  const float* qg;
  float* gate_out;
  const float* x;
  u16* Xn;
  int row0;
};
__global__ __launch_bounds__(256) void x34q_norm_kernel(X34Params p) {
  __shared__ __align__(16) u16 ldsA[3][2048];
  __shared__ __align__(16) u16 ldsB1[3][2048];
  __shared__ __align__(16) u16 ldsB2[3][2048];
  const int bid = blockIdx.x, tid = threadIdx.x;
  if (bid > 512) {
    norm_rows8(p.x, p.Xn, p.row0 + (bid - 513) * 8, tid, (float*)&ldsA[0][0]);
    return;
  }
  if (bid == 512) {  // gate softmax
    float* red = (float*)&ldsA[0][0];
    const float4 v = ((const float4*)p.qg)[tid];
    float mx = fmaxf(fmaxf(v.x, v.y), fmaxf(v.z, v.w));
    for (int o = 32; o; o >>= 1) mx = fmaxf(mx, __shfl_xor(mx, o));
    if ((tid & 63) == 0) red[tid >> 6] = mx;
    __syncthreads();
    const float M = fmaxf(fmaxf(red[0], red[1]), fmaxf(red[2], red[3]));
    __syncthreads();
    const float e0 = __expf(v.x - M), e1 = __expf(v.y - M),
                e2 = __expf(v.z - M), e3 = __expf(v.w - M);
    float s = e0 + e1 + e2 + e3;
    for (int o = 32; o; o >>= 1) s += __shfl_xor(s, o);
    if ((tid & 63) == 0) red[tid >> 6] = s;
    __syncthreads();
    const float S = red[0] + red[1] + red[2] + red[3];
    const float4 o4 = {e0 / S, e1 / S, e2 / S, e3 / S};
    ((float4*)p.gate_out)[tid] = o4;
    return;
  }
  const int mz = bid >> 8, t = bid & 255;
  const int bi = t >> 4, bj = t & 15;
  const u16* Ag = p.X2[mz];
  const u16* B1g = p.X[mz];
  const u16* B2g = p.X2[mz];
  const int w = tid >> 6, lane = tid & 63;
  const int wr = w >> 1, wc = w & 1;
  f32x4 acc3[2][2], acc4[2][2];
#pragma unroll
  for (int m = 0; m < 2; ++m)
#pragma unroll
    for (int n = 0; n < 2; ++n) {
      acc3[m][n] = f32x4{0.f, 0.f, 0.f, 0.f};
      acc4[m][n] = f32x4{0.f, 0.f, 0.f, 0.f};
    }
  const int srow = tid >> 2, sc = tid & 3;   // stage: row 0..63, chunk 0..3

  auto stage = [&](int buf, int s) {   // 3 g2l16 per thread (one per array)
    const int k0 = s * 32;
    const int csrc = sc ^ (srow & 3);  // inverse swizzle on global source
    g2l16(Ag + (size_t)(bi * 64 + srow) * D + k0 + csrc * 8,
          (char*)&ldsA[buf][0] + tid * 16);
    g2l16(B1g + (size_t)(bj * 64 + srow) * D + k0 + csrc * 8,
          (char*)&ldsB1[buf][0] + tid * 16);
    g2l16(B2g + (size_t)(bj * 64 + srow) * D + k0 + csrc * 8,
          (char*)&ldsB2[buf][0] + tid * 16);
  };
  const int h4 = lane >> 4;  // 8-elem chunk within the 32-wide K step
  auto compute = [&](int buf) {
    short8 a[2], b1[2], b2[2];
#pragma unroll
    for (int m = 0; m < 2; ++m) {
      const int row = wr * 32 + m * 16 + (lane & 15);
      const int off = row * 64 + ((h4 ^ (row & 3)) << 4);
      a[m] = *(const short8*)((const char*)&ldsA[buf][0] + off);
    }
#pragma unroll
    for (int n = 0; n < 2; ++n) {
      const int row = wc * 32 + n * 16 + (lane & 15);
      const int off = row * 64 + ((h4 ^ (row & 3)) << 4);
      b1[n] = *(const short8*)((const char*)&ldsB1[buf][0] + off);
      b2[n] = *(const short8*)((const char*)&ldsB2[buf][0] + off);
    }
#pragma unroll
    for (int m = 0; m < 2; ++m)
#pragma unroll
      for (int n = 0; n < 2; ++n) {
        acc3[m][n] = __builtin_amdgcn_mfma_f32_16x16x32_bf16(
            a[m], b1[n], acc3[m][n], 0, 0, 0);
        acc4[m][n] = __builtin_amdgcn_mfma_f32_16x16x32_bf16(
            a[m], b2[n], acc4[m][n], 0, 0, 0);
      }
  };

  stage(0, 0); stage(1, 1);   // 6 loads in flight (2-ahead)
  for (int s = 0; s < 30; ++s) {
    WAITV(3);                          // own G(s) landed
    __builtin_amdgcn_s_barrier();
    __builtin_amdgcn_sched_barrier(0);
    stage((s + 2) % 3, s + 2);         // overwrites buf(s-1): reads done
    compute(s % 3);
  }
  WAITV(3);
  __builtin_amdgcn_s_barrier();
  __builtin_amdgcn_sched_barrier(0);
  compute(30 % 3);
  WAITV(0);
  __builtin_amdgcn_s_barrier();
  __builtin_amdgcn_sched_barrier(0);
  compute(31 % 3);

  const int or0 = bi * 64 + wr * 32, oc0 = bj * 64 + wc * 32;
#pragma unroll
  for (int m = 0; m < 2; ++m)
#pragma unroll
    for (int n = 0; n < 2; ++n) {
      const int row0 = or0 + m * 16 + (lane >> 4) * 4;
      const int col = oc0 + n * 16 + (lane & 15);
#pragma unroll
      for (int r = 0; r < 4; ++r) {
        const size_t idx = (size_t)(row0 + r) * D + col;
        const u16 x3v = f2bf(-acc3[m][n][r]);
        const u16 x4v = f2bf(acc4[m][n][r]);
        p.X3[mz][idx] = x3v;
        p.X4[mz][idx] = x4v;
        const float d = (row0 + r == col) ? 1.f : 0.f;
        const float xf = bf2f(p.X[mz][idx]);
        const float x2f = bf2f(p.X2[mz][idx]);
        const float x3f = bf2f(x3v), x4f = bf2f(x4v);
        p.q0[mz][idx] = d + xf + x2f * 0.5f + x3f * (1.f / 6.f);
        p.q1t[mz][idx] =
            f2bf(d * (1.f / 24.f) - xf * (1.f / 120.f) + x2f * (1.f / 720.f) -
                 x3f * (1.f / 5040.f) + x4f * (1.f / 40320.f));
      }
    }
}

// ---------------------------------------------------------------------------
// main GEMM (r10 pipeline; r13: bj-fastest dispatch for Xn-panel locality)
// out[r][c] = (f(Xn,W) + bias[c])^2 * gate[c]
// 256x256 tile, BK=32, 8 waves (2x4), 4 LDS bufs (128 KiB), 3-ahead
// prefetch, counted vmcnt(8) before raw s_barrier (no full drains).
__global__ __launch_bounds__(512, 1) void main_gemm_kernel(
    const u16* __restrict__ Xn, const u16* __restrict__ Wm,
    const float* __restrict__ bias, const float* __restrict__ gate,
    float* __restrict__ out) {
  const int tid = threadIdx.x;
  const int wid = tid >> 6, lane = tid & 63;
  const int wr = wid >> 2, wc = wid & 3;   // 2 x 4 waves
  __shared__ u16 lds[4 * 16384];           // 4 bufs x (A 16KB + B 16KB)
  f32x4 acc[8][4];
#pragma unroll
  for (int m = 0; m < 8; ++m)
#pragma unroll
    for (int n = 0; n < 4; ++n) acc[m][n] = f32x4{0.f, 0.f, 0.f, 0.f};

  const int bj = blockIdx.x, bi = blockIdx.y;   // bj fastest: 4 x 128
  const int r_ = tid >> 2;   // 0..127
  const int c_ = tid & 3;

  auto stage = [&](int s) {
    char* base = (char*)lds + (s & 3) * 32768;
#pragma unroll
    for (int pp = 0; pp < 2; ++pp) {
      const int row = pp * 128 + r_;
      const int csrc = c_ ^ ((row >> 1) & 3);  // inverse swizzle on source
      g2l16(Xn + (size_t)(bi * 256 + row) * D + s * 32 + csrc * 8,
            base + pp * 8192 + tid * 16);
      g2l16(Wm + (size_t)(bj * 256 + row) * D + s * 32 + csrc * 8,
            base + 16384 + pp * 8192 + tid * 16);
    }
  };

  const int h = lane >> 4;  // k-chunk 0..3 within 32-wide step
  auto compute = [&](int s) {
    const char* base = (const char*)lds + (s & 3) * 32768;
    short8 a[8], b[4];
#pragma unroll
    for (int m = 0; m < 8; ++m) {
      const int row = wr * 128 + m * 16 + (lane & 15);
      const int off = row * 64 + ((h ^ ((row >> 1) & 3)) << 4);
      a[m] = *(const short8*)(base + off);
    }
#pragma unroll
    for (int n = 0; n < 4; ++n) {
      const int row = wc * 64 + n * 16 + (lane & 15);
      const int off = 16384 + row * 64 + ((h ^ ((row >> 1) & 3)) << 4);
      b[n] = *(const short8*)(base + off);
    }
    __builtin_amdgcn_s_setprio(1);
#pragma unroll
    for (int m = 0; m < 8; ++m)
#pragma unroll
      for (int n = 0; n < 4; ++n)
        acc[m][n] = __builtin_amdgcn_mfma_f32_16x16x32_bf16(a[m], b[n],
                                                            acc[m][n], 0, 0, 0);
    __builtin_amdgcn_s_setprio(0);
  };

  stage(0); stage(1); stage(2);   // 12 loads in flight
  for (int s = 0; s < 29; ++s) {
    WAITV(8);
    __builtin_amdgcn_s_barrier();
    __builtin_amdgcn_sched_barrier(0);
    stage(s + 3);
    compute(s);
  }
  WAITV(8);
  __builtin_amdgcn_s_barrier();
  __builtin_amdgcn_sched_barrier(0);
  compute(29);
  WAITV(4);
  __builtin_amdgcn_s_barrier();
  __builtin_amdgcn_sched_barrier(0);
  compute(30);
  WAITV(0);
  __builtin_amdgcn_s_barrier();
  __builtin_amdgcn_sched_barrier(0);
  compute(31);

  const int or0 = bi * 256 + wr * 128, oc0 = bj * 256 + wc * 64;
#pragma unroll
  for (int m = 0; m < 8; ++m)
#pragma unroll
    for (int n = 0; n < 4; ++n) {
      const int col = oc0 + n * 16 + (lane & 15);
      const float bc = bias[col], gc = gate[col];
#pragma unroll
      for (int r = 0; r < 4; ++r) {
        const int row = or0 + m * 16 + (lane >> 4) * 4 + r;
        const float t = acc[m][n][r] + bc;
        out[(size_t)row * D + col] = t * t * gc;
      }
    }
}

// ---------------------------------------------------------------------------
extern "C" void kernel_launch(void* const* d_in, const int* in_sizes, int n_in,
                              void* d_out, int out_size, void* d_ws,
                              size_t ws_size, hipStream_t stream) {
  (void)in_sizes; (void)n_in; (void)out_size; (void)ws_size;
  const float* inp = (const float*)d_in[0];
  const float* Mr = (const float*)d_in[1];
  const float* Mi = (const float*)d_in[2];
  const float* bias = (const float*)d_in[3];
  const float* qg = (const float*)d_in[4];
  float* out = (float*)d_out;
  float* gate_out = out + (size_t)32768 * 1024;

  char* ws = (char*)d_ws;
  u16* Xn = (u16*)ws;  // 64 MB
  // per-matrix region (16 MB): 6 bf16 slots (2 MB) + q0 (4 MB f32).
  // lifetimes: s0 X->E3, s1 X2->Et->E3t, s2 X3->E1, s3 X4->E2,
  //            s4 q1t->E1t, s5 E2t
  auto slot = [&](int m, int s) -> u16* {
    return (u16*)(ws + 67108864 + (size_t)m * 16777216 + (size_t)s * 2097152);
  };
  auto q0p = [&](int m) -> float* {
    return (float*)(ws + 67108864 + (size_t)m * 16777216 + 12582912);
  };
  u16* W = (u16*)(ws + 100663296);  // 96 MB: 2 MB

  // normalize rows: 8 launches x 4096 rows (512 blocks of 8 rows each)
  const int CH = 4096, NB = 512;
  int row0 = 0;

  // L1: skew
  {
    SkewParams sp{Mr, Mi, slot(0, 0), slot(1, 0), inp, Xn, row0};
    skew_norm_kernel<<<512 + NB, 256, 0, stream>>>(sp);
    row0 += CH;
  }
  GNParams gp{};
  gp.x = inp; gp.Xn = Xn;
  // L2: X2 = -f(X,X) -> s1
  for (int m = 0; m < 2; ++m)
    gp.jobs[m] = CJob{slot(m, 0), slot(m, 0), nullptr, slot(m, 1), nullptr,
                      -1.f};
  gp.njobs = 1024; gp.row0 = row0;
  gemm_norm_kernel<<<1024 + NB, 256, 0, stream>>>(gp);
  row0 += CH;
  // L3: fused X3/X4 + buildq + gate
  {
    X34Params xp{};
    for (int m = 0; m < 2; ++m) {
      xp.X[m] = slot(m, 0); xp.X2[m] = slot(m, 1);
      xp.X3[m] = slot(m, 2); xp.X4[m] = slot(m, 3);
      xp.q1t[m] = slot(m, 4); xp.q0[m] = q0p(m);
    }
    xp.qg = qg; xp.gate_out = gate_out;
    xp.x = inp; xp.Xn = Xn; xp.row0 = row0;
    x34q_norm_kernel<<<513 + NB, 256, 0, stream>>>(xp);
    row0 += CH;
  }
  // L4: E = f(X4, q1t) + q0 -> s0, dual Et -> s1
  for (int m = 0; m < 2; ++m)
    gp.jobs[m] = CJob{slot(m, 3), slot(m, 4), q0p(m), slot(m, 0), slot(m, 1),
                      1.f};
  gp.njobs = 1024; gp.row0 = row0;
  gemm_norm_kernel<<<1024 + NB, 256, 0, stream>>>(gp);
  row0 += CH;
  // L5: sq1: E1 = f(E,Et) -> s2, dual E1t -> s4
  for (int m = 0; m < 2; ++m)
    gp.jobs[m] = CJob{slot(m, 0), slot(m, 1), nullptr, slot(m, 2), slot(m, 4),
                      1.f};
  gp.row0 = row0;
  gemm_norm_kernel<<<1024 + NB, 256, 0, stream>>>(gp);
  row0 += CH;
  // L6: sq2: E2 = f(E1,E1t) -> s3, dual E2t -> s5
  for (int m = 0; m < 2; ++m)
    gp.jobs[m] = CJob{slot(m, 2), slot(m, 4), nullptr, slot(m, 3), slot(m, 5),
                      1.f};
  gp.row0 = row0;
  gemm_norm_kernel<<<1024 + NB, 256, 0, stream>>>(gp);
  row0 += CH;
  // L7: sq3: E3 = f(E2,E2t) -> s0, dual E3t -> s1
  for (int m = 0; m < 2; ++m)
    gp.jobs[m] = CJob{slot(m, 3), slot(m, 5), nullptr, slot(m, 0), slot(m, 1),
                      1.f};
  gp.row0 = row0;
  gemm_norm_kernel<<<1024 + NB, 256, 0, stream>>>(gp);
  row0 += CH;
  // L8: W = U^T = f(E3t_B, E3_A)
  gp.jobs[0] = CJob{slot(1, 1), slot(0, 0), nullptr, W, nullptr, 1.f};
  gp.njobs = 512; gp.row0 = row0;
  gemm_norm_kernel<<<512 + NB, 256, 0, stream>>>(gp);

  main_gemm_kernel<<<dim3(4, 128), 512, 0, stream>>>(Xn, W, bias, gate_out,
                                                     out);
}

// Round 14
// 207.516 us; speedup vs baseline: 1.1186x; 1.1186x over previous
//
#include <hip/hip_runtime.h>

// ---------------------------------------------------------------------------
// RefinedQuantumEntanglementLayer on MI355X (gfx950)
//
// out = (l2norm(x) @ expm(Mr-Mr^T) @ expm(Mi-Mi^T) + bias)^2 * softmax(qg)
//
// r14: revert r13's two regressions (bj-fastest main dispatch: FETCH
// 82->135MB +3.5us; 32x64 chain tiles: +50% staging traffic) back to the
// r12 structure, and shorten the chain with s=2 scaling (X = A/4, same
// deg-8 PS): one fewer squaring -> 7 chain launches instead of 8
// (~17us/launch marginal, r9/r12 data). Precision: ||X||~2.26, deg-8
// remainder 5.4e-3 at the spectral edge, x4 after 2 squarings -- projected
// through eigenvector mixing contributes <~1e-7 to absmax; one fewer
// squaring also halves bf16-noise amplification. Expect absmax 3-8e-7.
//
// Chain math (deg-8 Paterson-Stockmeyer, s=2):  [f(A,B) = A*B^T]
//   X2 = -f(X,X); X3 = -f(X2,X); X4 = f(X2,X2)
//   q0 = I+X+X2/2+X3/6 (f32); q1t = elementwise-transposed q1 (odd flips)
//   E  = f(X4,q1t)+q0 [dual-write -> Et]
//   squarings E1 = f(E,Et), E2 = f(E1,E1t) [duals E1t,E2t]
//   W = U^T = f(E2t_B, E2_A); main: out = f(Xn,W) epi (.+bias)^2*gate
// main (r10/r12): 256^2 tile BK=32 4-buf counted-vmcnt, bi-fastest.
// ---------------------------------------------------------------------------

typedef unsigned int u32;
typedef unsigned short u16;
typedef __attribute__((ext_vector_type(8))) short short8;   // 8 x bf16 raw
typedef __attribute__((ext_vector_type(4))) float f32x4;

#define GLOBAL_AS __attribute__((address_space(1)))
#define LDS_AS    __attribute__((address_space(3)))

constexpr int D = 1024;
constexpr float EXPM_SCALE = 1.0f / 4.0f;   // s = 2 squarings

__device__ __forceinline__ u16 f2bf(float f) {
  union { float f; u32 u; } v; v.f = f;
  u32 r = (v.u + 0x7FFFu + ((v.u >> 16) & 1u)) >> 16;
  return (u16)r;
}
__device__ __forceinline__ float bf2f(u16 u) {
  union { u32 u; float f; } v; v.u = ((u32)u) << 16;
  return v.f;
}

// async global->LDS, 16B per lane; lds base must be wave-uniform.
__device__ __forceinline__ void g2l16(const void* g, void* l) {
  __builtin_amdgcn_global_load_lds((const GLOBAL_AS u32*)g, (LDS_AS u32*)l,
                                   16, 0, 0);
}

#define WAITV(N)                                                   \
  do {                                                             \
    asm volatile("s_waitcnt vmcnt(" #N ")" ::: "memory");          \
    __builtin_amdgcn_sched_barrier(0);                             \
  } while (0)

// ---------------------------------------------------------------------------
// normalize 8 rows of x -> bf16 (tail body shared by chain launches)
__device__ void norm_rows8(const float* __restrict__ x, u16* __restrict__ Xn,
                           int r0, int tid, float* sred) {
  float4 v[8];
#pragma unroll
  for (int i = 0; i < 8; ++i)
    v[i] = ((const float4*)(x + (size_t)(r0 + i) * D))[tid];
  float ss[8];
#pragma unroll
  for (int i = 0; i < 8; ++i)
    ss[i] = v[i].x * v[i].x + v[i].y * v[i].y + v[i].z * v[i].z +
            v[i].w * v[i].w;
  for (int o = 32; o; o >>= 1)
#pragma unroll
    for (int i = 0; i < 8; ++i) ss[i] += __shfl_down(ss[i], o);
  const int w = tid >> 6;
  if ((tid & 63) == 0)
#pragma unroll
    for (int i = 0; i < 8; ++i) sred[i * 4 + w] = ss[i];
  __syncthreads();
#pragma unroll
  for (int i = 0; i < 8; ++i) {
    const float tot =
        sred[i * 4 + 0] + sred[i * 4 + 1] + sred[i * 4 + 2] + sred[i * 4 + 3];
    const float inv = rsqrtf(fmaxf(tot, 1e-12f));
    ushort4 o4;
    o4.x = f2bf(v[i].x * inv); o4.y = f2bf(v[i].y * inv);
    o4.z = f2bf(v[i].z * inv); o4.w = f2bf(v[i].w * inv);
    ((ushort4*)(Xn + (size_t)(r0 + i) * D))[tid] = o4;
  }
}

// ---------------------------------------------------------------------------
// L1: skew tiles (512 jobs) + norm tail
struct SkewParams {
  const float *Mr, *Mi;
  u16 *X0, *X1;
  const float* x;
  u16* Xn;
  int row0;
};
__global__ __launch_bounds__(256) void skew_norm_kernel(SkewParams p) {
  __shared__ __align__(16) float t2[64][67];
  const int bid = blockIdx.x, tid = threadIdx.x;
  if (bid >= 512) {
    norm_rows8(p.x, p.Xn, p.row0 + (bid - 512) * 8, tid, &t2[0][0]);
    return;
  }
  const int z = bid >> 8, t = bid & 255;
  const float* M = z ? p.Mi : p.Mr;
  u16* X = z ? p.X1 : p.X0;
  const int bi = t >> 4, bj = t & 15;
  const int r0 = tid >> 4, c0 = (tid & 15) * 4;
  float4 own[4];
#pragma unroll
  for (int i = 0; i < 4; ++i) {
    const int r = i * 16 + r0;
    own[i] = *(const float4*)(M + (size_t)(bi * 64 + r) * D + bj * 64 + c0);
    const float4 tr =
        *(const float4*)(M + (size_t)(bj * 64 + r) * D + bi * 64 + c0);
    t2[r][c0 + 0] = tr.x; t2[r][c0 + 1] = tr.y;
    t2[r][c0 + 2] = tr.z; t2[r][c0 + 3] = tr.w;
  }
  __syncthreads();
#pragma unroll
  for (int i = 0; i < 4; ++i) {
    const int r = i * 16 + r0;
    const float o[4] = {own[i].x, own[i].y, own[i].z, own[i].w};
    ushort4 hv;
    u16* hp = (u16*)&hv;
#pragma unroll
    for (int j = 0; j < 4; ++j)
      hp[j] = f2bf((o[j] - t2[c0 + j][r]) * EXPM_SCALE);
    *(ushort4*)(X + (size_t)(bi * 64 + r) * D + bj * 64 + c0) = hv;
  }
}

// ---------------------------------------------------------------------------
// generic chain GEMM round + norm tail (r12 body). 64x64 tile, BK=64,
// 4 waves (2x2, 32x32 each), 3 LDS bufs (48KB -> 3 blocks/CU), 2-ahead
// prefetch, counted vmcnt(4), tail 4/0.
struct CJob {
  const u16 *A, *B;
  const float* C;
  u16 *Dst, *DT;
  float alpha;
};
struct GNParams {
  CJob jobs[2];
  int njobs;
  const float* x;
  u16* Xn;
  int row0;
};
__global__ __launch_bounds__(256) void gemm_norm_kernel(GNParams p) {
  __shared__ __align__(16) u16 ldsA[3][4096];
  __shared__ __align__(16) u16 ldsB[3][4096];
  const int bid = blockIdx.x, tid = threadIdx.x;
  if (bid >= p.njobs) {
    norm_rows8(p.x, p.Xn, p.row0 + (bid - p.njobs) * 8, tid,
               (float*)&ldsA[0][0]);
    return;
  }
  const CJob jb = p.jobs[bid >> 8];
  const int bi = (bid >> 4) & 15, bj = bid & 15;
  const int w = tid >> 6, lane = tid & 63;
  const int wr = w >> 1, wc = w & 1;
  f32x4 acc[2][2];
#pragma unroll
  for (int m = 0; m < 2; ++m)
#pragma unroll
    for (int n = 0; n < 2; ++n) acc[m][n] = f32x4{0.f, 0.f, 0.f, 0.f};
  const int r_l = lane >> 3, c_l = lane & 7;

  auto stage = [&](int buf, int kt) {   // 4 g2l16 per thread
    const int k0 = kt * 64;
#pragma unroll
    for (int pp = 0; pp < 2; ++pp) {
      const int row = pp * 32 + w * 8 + r_l;
      const int chunk = c_l ^ (row & 7);  // inverse swizzle on global source
      g2l16(jb.A + (size_t)(bi * 64 + row) * D + k0 + chunk * 8,
            (char*)&ldsA[buf][0] + pp * 4096 + w * 1024);
      g2l16(jb.B + (size_t)(bj * 64 + row) * D + k0 + chunk * 8,
            (char*)&ldsB[buf][0] + pp * 4096 + w * 1024);
    }
  };
  auto compute = [&](int buf) {
#pragma unroll
    for (int h = 0; h < 2; ++h) {
      const int kk = h * 32 + (lane >> 4) * 8;
      short8 a[2], b[2];
#pragma unroll
      for (int m = 0; m < 2; ++m) {
        const int row = wr * 32 + m * 16 + (lane & 15);
        const int off = row * 128 + ((kk * 2) ^ ((row & 7) << 4));
        a[m] = *(const short8*)((const char*)&ldsA[buf][0] + off);
      }
#pragma unroll
      for (int n = 0; n < 2; ++n) {
        const int row = wc * 32 + n * 16 + (lane & 15);
        const int off = row * 128 + ((kk * 2) ^ ((row & 7) << 4));
        b[n] = *(const short8*)((const char*)&ldsB[buf][0] + off);
      }
#pragma unroll
      for (int m = 0; m < 2; ++m)
#pragma unroll
        for (int n = 0; n < 2; ++n)
          acc[m][n] = __builtin_amdgcn_mfma_f32_16x16x32_bf16(
              a[m], b[n], acc[m][n], 0, 0, 0);
    }
  };

  stage(0, 0); stage(1, 1);   // 8 loads in flight (2-ahead)
  for (int s = 0; s < 14; ++s) {
    WAITV(4);                         // own G(s) landed (G(s+1) may fly)
    __builtin_amdgcn_s_barrier();     // all threads' G(s) landed;
    __builtin_amdgcn_sched_barrier(0);//  all threads finished compute(s-1)
    stage((s + 2) % 3, s + 2);        // overwrites buf(s-1): reads done
    compute(s % 3);
  }
  WAITV(4);
  __builtin_amdgcn_s_barrier();
  __builtin_amdgcn_sched_barrier(0);
  compute(14 % 3);
  WAITV(0);
  __builtin_amdgcn_s_barrier();
  __builtin_amdgcn_sched_barrier(0);
  compute(15 % 3);

  const int or0 = bi * 64 + wr * 32, oc0 = bj * 64 + wc * 32;
#pragma unroll
  for (int m = 0; m < 2; ++m)
#pragma unroll
    for (int n = 0; n < 2; ++n) {
      const int row0 = or0 + m * 16 + (lane >> 4) * 4;
      const int col = oc0 + n * 16 + (lane & 15);
      ushort4 dv;
      u16* dp = (u16*)&dv;
#pragma unroll
      for (int r = 0; r < 4; ++r) {
        float v = acc[m][n][r] * jb.alpha;
        if (jb.C) v += jb.C[(size_t)(row0 + r) * D + col];
        dp[r] = f2bf(v);
        jb.Dst[(size_t)(row0 + r) * D + col] = dp[r];
      }
      if (jb.DT)  // transposed tile: DT[col][row0..row0+3], one 8B store
        *(ushort4*)(jb.DT + (size_t)col * D + row0) = dv;
    }
}

// ---------------------------------------------------------------------------
// L3: fused X3/X4 + buildq + gate + norm tail (r12 body). BK=32, 3 arrays
// x 3 bufs x 4KB = 36KB (4 blocks/CU), 2-ahead, counted vmcnt(3), tail 3/0.
struct X34Params {
  const u16 *X[2], *X2[2];
  u16 *X3[2], *X4[2], *q1t[2];
  float* q0[2];
  const float* qg;
  float* gate_out;
  const float* x;
  u16* Xn;
  int row0;
};
__global__ __launch_bounds__(256) void x34q_norm_kernel(X34Params p) {
  __shared__ __align__(16) u16 ldsA[3][2048];
  __shared__ __align__(16) u16 ldsB1[3][2048];
  __shared__ __align__(16) u16 ldsB2[3][2048];
  const int bid = blockIdx.x, tid = threadIdx.x;
  if (bid > 512) {
    norm_rows8(p.x, p.Xn, p.row0 + (bid - 513) * 8, tid, (float*)&ldsA[0][0]);
    return;
  }
  if (bid == 512) {  // gate softmax
    float* red = (float*)&ldsA[0][0];
    const float4 v = ((const float4*)p.qg)[tid];
    float mx = fmaxf(fmaxf(v.x, v.y), fmaxf(v.z, v.w));
    for (int o = 32; o; o >>= 1) mx = fmaxf(mx, __shfl_xor(mx, o));
    if ((tid & 63) == 0) red[tid >> 6] = mx;
    __syncthreads();
    const float M = fmaxf(fmaxf(red[0], red[1]), fmaxf(red[2], red[3]));
    __syncthreads();
    const float e0 = __expf(v.x - M), e1 = __expf(v.y - M),
                e2 = __expf(v.z - M), e3 = __expf(v.w - M);
    float s = e0 + e1 + e2 + e3;
    for (int o = 32; o; o >>= 1) s += __shfl_xor(s, o);
    if ((tid & 63) == 0) red[tid >> 6] = s;
    __syncthreads();
    const float S = red[0] + red[1] + red[2] + red[3];
    const float4 o4 = {e0 / S, e1 / S, e2 / S, e3 / S};
    ((float4*)p.gate_out)[tid] = o4;
    return;
  }
  const int mz = bid >> 8, t = bid & 255;
  const int bi = t >> 4, bj = t & 15;
  const u16* Ag = p.X2[mz];
  const u16* B1g = p.X[mz];
  const u16* B2g = p.X2[mz];
  const int w = tid >> 6, lane = tid & 63;
  const int wr = w >> 1, wc = w & 1;
  f32x4 acc3[2][2], acc4[2][2];
#pragma unroll
  for (int m = 0; m < 2; ++m)
#pragma unroll
    for (int n = 0; n < 2; ++n) {
      acc3[m][n] = f32x4{0.f, 0.f, 0.f, 0.f};
      acc4[m][n] = f32x4{0.f, 0.f, 0.f, 0.f};
    }
  const int srow = tid >> 2, sc = tid & 3;   // stage: row 0..63, chunk 0..3

  auto stage = [&](int buf, int s) {   // 3 g2l16 per thread (one per array)
    const int k0 = s * 32;
    const int csrc = sc ^ (srow & 3);  // inverse swizzle on global source
    g2l16(Ag + (size_t)(bi * 64 + srow) * D + k0 + csrc * 8,
          (char*)&ldsA[buf][0] + tid * 16);
    g2l16(B1g + (size_t)(bj * 64 + srow) * D + k0 + csrc * 8,
          (char*)&ldsB1[buf][0] + tid * 16);
    g2l16(B2g + (size_t)(bj * 64 + srow) * D + k0 + csrc * 8,
          (char*)&ldsB2[buf][0] + tid * 16);
  };
  const int h4 = lane >> 4;  // 8-elem chunk within the 32-wide K step
  auto compute = [&](int buf) {
    short8 a[2], b1[2], b2[2];
#pragma unroll
    for (int m = 0; m < 2; ++m) {
      const int row = wr * 32 + m * 16 + (lane & 15);
      const int off = row * 64 + ((h4 ^ (row & 3)) << 4);
      a[m] = *(const short8*)((const char*)&ldsA[buf][0] + off);
    }
#pragma unroll
    for (int n = 0; n < 2; ++n) {
      const int row = wc * 32 + n * 16 + (lane & 15);
      const int off = row * 64 + ((h4 ^ (row & 3)) << 4);
      b1[n] = *(const short8*)((const char*)&ldsB1[buf][0] + off);
      b2[n] = *(const short8*)((const char*)&ldsB2[buf][0] + off);
    }
#pragma unroll
    for (int m = 0; m < 2; ++m)
#pragma unroll
      for (int n = 0; n < 2; ++n) {
        acc3[m][n] = __builtin_amdgcn_mfma_f32_16x16x32_bf16(
            a[m], b1[n], acc3[m][n], 0, 0, 0);
        acc4[m][n] = __builtin_amdgcn_mfma_f32_16x16x32_bf16(
            a[m], b2[n], acc4[m][n], 0, 0, 0);
      }
  };

  stage(0, 0); stage(1, 1);   // 6 loads in flight (2-ahead)
  for (int s = 0; s < 30; ++s) {
    WAITV(3);                          // own G(s) landed
    __builtin_amdgcn_s_barrier();
    __builtin_amdgcn_sched_barrier(0);
    stage((s + 2) % 3, s + 2);         // overwrites buf(s-1): reads done
    compute(s % 3);
  }
  WAITV(3);
  __builtin_amdgcn_s_barrier();
  __builtin_amdgcn_sched_barrier(0);
  compute(30 % 3);
  WAITV(0);
  __builtin_amdgcn_s_barrier();
  __builtin_amdgcn_sched_barrier(0);
  compute(31 % 3);

  const int or0 = bi * 64 + wr * 32, oc0 = bj * 64 + wc * 32;
#pragma unroll
  for (int m = 0; m < 2; ++m)
#pragma unroll
    for (int n = 0; n < 2; ++n) {
      const int row0 = or0 + m * 16 + (lane >> 4) * 4;
      const int col = oc0 + n * 16 + (lane & 15);
#pragma unroll
      for (int r = 0; r < 4; ++r) {
        const size_t idx = (size_t)(row0 + r) * D + col;
        const u16 x3v = f2bf(-acc3[m][n][r]);
        const u16 x4v = f2bf(acc4[m][n][r]);
        p.X3[mz][idx] = x3v;
        p.X4[mz][idx] = x4v;
        const float d = (row0 + r == col) ? 1.f : 0.f;
        const float xf = bf2f(p.X[mz][idx]);
        const float x2f = bf2f(p.X2[mz][idx]);
        const float x3f = bf2f(x3v), x4f = bf2f(x4v);
        p.q0[mz][idx] = d + xf + x2f * 0.5f + x3f * (1.f / 6.f);
        p.q1t[mz][idx] =
            f2bf(d * (1.f / 24.f) - xf * (1.f / 120.f) + x2f * (1.f / 720.f) -
                 x3f * (1.f / 5040.f) + x4f * (1.f / 40320.f));
      }
    }
}

// ---------------------------------------------------------------------------
// main GEMM (r10/r12, unchanged; bi-fastest dispatch — r13's bj-fastest
// raised FETCH 82->135MB and cost 3.5us).
// out[r][c] = (f(Xn,W) + bias[c])^2 * gate[c]
// 256x256 tile, BK=32, 8 waves (2x4), 4 LDS bufs (128 KiB), 3-ahead
// prefetch, counted vmcnt(8) before raw s_barrier (no full drains).
__global__ __launch_bounds__(512, 1) void main_gemm_kernel(
    const u16* __restrict__ Xn, const u16* __restrict__ Wm,
    const float* __restrict__ bias, const float* __restrict__ gate,
    float* __restrict__ out) {
  const int tid = threadIdx.x;
  const int wid = tid >> 6, lane = tid & 63;
  const int wr = wid >> 2, wc = wid & 3;   // 2 x 4 waves
  __shared__ u16 lds[4 * 16384];           // 4 bufs x (A 16KB + B 16KB)
  f32x4 acc[8][4];
#pragma unroll
  for (int m = 0; m < 8; ++m)
#pragma unroll
    for (int n = 0; n < 4; ++n) acc[m][n] = f32x4{0.f, 0.f, 0.f, 0.f};

  const int bi = blockIdx.x, bj = blockIdx.y;   // 128 x 4, bi fastest
  const int r_ = tid >> 2;   // 0..127
  const int c_ = tid & 3;

  auto stage = [&](int s) {
    char* base = (char*)lds + (s & 3) * 32768;
#pragma unroll
    for (int pp = 0; pp < 2; ++pp) {
      const int row = pp * 128 + r_;
      const int csrc = c_ ^ ((row >> 1) & 3);  // inverse swizzle on source
      g2l16(Xn + (size_t)(bi * 256 + row) * D + s * 32 + csrc * 8,
            base + pp * 8192 + tid * 16);
      g2l16(Wm + (size_t)(bj * 256 + row) * D + s * 32 + csrc * 8,
            base + 16384 + pp * 8192 + tid * 16);
    }
  };

  const int h = lane >> 4;  // k-chunk 0..3 within 32-wide step
  auto compute = [&](int s) {
    const char* base = (const char*)lds + (s & 3) * 32768;
    short8 a[8], b[4];
#pragma unroll
    for (int m = 0; m < 8; ++m) {
      const int row = wr * 128 + m * 16 + (lane & 15);
      const int off = row * 64 + ((h ^ ((row >> 1) & 3)) << 4);
      a[m] = *(const short8*)(base + off);
    }
#pragma unroll
    for (int n = 0; n < 4; ++n) {
      const int row = wc * 64 + n * 16 + (lane & 15);
      const int off = 16384 + row * 64 + ((h ^ ((row >> 1) & 3)) << 4);
      b[n] = *(const short8*)(base + off);
    }
    __builtin_amdgcn_s_setprio(1);
#pragma unroll
    for (int m = 0; m < 8; ++m)
#pragma unroll
      for (int n = 0; n < 4; ++n)
        acc[m][n] = __builtin_amdgcn_mfma_f32_16x16x32_bf16(a[m], b[n],
                                                            acc[m][n], 0, 0, 0);
    __builtin_amdgcn_s_setprio(0);
  };

  stage(0); stage(1); stage(2);   // 12 loads in flight
  for (int s = 0; s < 29; ++s) {
    WAITV(8);
    __builtin_amdgcn_s_barrier();
    __builtin_amdgcn_sched_barrier(0);
    stage(s + 3);
    compute(s);
  }
  WAITV(8);
  __builtin_amdgcn_s_barrier();
  __builtin_amdgcn_sched_barrier(0);
  compute(29);
  WAITV(4);
  __builtin_amdgcn_s_barrier();
  __builtin_amdgcn_sched_barrier(0);
  compute(30);
  WAITV(0);
  __builtin_amdgcn_s_barrier();
  __builtin_amdgcn_sched_barrier(0);
  compute(31);

  const int or0 = bi * 256 + wr * 128, oc0 = bj * 256 + wc * 64;
#pragma unroll
  for (int m = 0; m < 8; ++m)
#pragma unroll
    for (int n = 0; n < 4; ++n) {
      const int col = oc0 + n * 16 + (lane & 15);
      const float bc = bias[col], gc = gate[col];
#pragma unroll
      for (int r = 0; r < 4; ++r) {
        const int row = or0 + m * 16 + (lane >> 4) * 4 + r;
        const float t = acc[m][n][r] + bc;
        out[(size_t)row * D + col] = t * t * gc;
      }
    }
}

// ---------------------------------------------------------------------------
extern "C" void kernel_launch(void* const* d_in, const int* in_sizes, int n_in,
                              void* d_out, int out_size, void* d_ws,
                              size_t ws_size, hipStream_t stream) {
  (void)in_sizes; (void)n_in; (void)out_size; (void)ws_size;
  const float* inp = (const float*)d_in[0];
  const float* Mr = (const float*)d_in[1];
  const float* Mi = (const float*)d_in[2];
  const float* bias = (const float*)d_in[3];
  const float* qg = (const float*)d_in[4];
  float* out = (float*)d_out;
  float* gate_out = out + (size_t)32768 * 1024;

  char* ws = (char*)d_ws;
  u16* Xn = (u16*)ws;  // 64 MB
  // per-matrix region (16 MB): 6 bf16 slots (2 MB) + q0 (4 MB f32).
  // lifetimes (s=2): s0 X->E, s1 X2->Et, s2 X3->E1, s3 X4->E2,
  //                  s4 q1t->E1t, s5 E2t
  auto slot = [&](int m, int s) -> u16* {
    return (u16*)(ws + 67108864 + (size_t)m * 16777216 + (size_t)s * 2097152);
  };
  auto q0p = [&](int m) -> float* {
    return (float*)(ws + 67108864 + (size_t)m * 16777216 + 12582912);
  };
  u16* W = (u16*)(ws + 100663296);  // 96 MB: 2 MB

  // normalize rows spread over the 7 chain launches:
  // L1-L6: 585 blocks x 8 rows = 4680 each; L7: 586 blocks = 4688.
  int row0 = 0;

  // L1: skew
  {
    SkewParams sp{Mr, Mi, slot(0, 0), slot(1, 0), inp, Xn, row0};
    skew_norm_kernel<<<512 + 585, 256, 0, stream>>>(sp);
    row0 += 4680;
  }
  GNParams gp{};
  gp.x = inp; gp.Xn = Xn;
  // L2: X2 = -f(X,X) -> s1
  for (int m = 0; m < 2; ++m)
    gp.jobs[m] = CJob{slot(m, 0), slot(m, 0), nullptr, slot(m, 1), nullptr,
                      -1.f};
  gp.njobs = 512; gp.row0 = row0;
  gemm_norm_kernel<<<512 + 585, 256, 0, stream>>>(gp);
  row0 += 4680;
  // L3: fused X3/X4 + buildq + gate
  {
    X34Params xp{};
    for (int m = 0; m < 2; ++m) {
      xp.X[m] = slot(m, 0); xp.X2[m] = slot(m, 1);
      xp.X3[m] = slot(m, 2); xp.X4[m] = slot(m, 3);
      xp.q1t[m] = slot(m, 4); xp.q0[m] = q0p(m);
    }
    xp.qg = qg; xp.gate_out = gate_out;
    xp.x = inp; xp.Xn = Xn; xp.row0 = row0;
    x34q_norm_kernel<<<513 + 585, 256, 0, stream>>>(xp);
    row0 += 4680;
  }
  // L4: E = f(X4, q1t) + q0 -> s0, dual Et -> s1   (X, X2 dead)
  for (int m = 0; m < 2; ++m)
    gp.jobs[m] = CJob{slot(m, 3), slot(m, 4), q0p(m), slot(m, 0), slot(m, 1),
                      1.f};
  gp.njobs = 512; gp.row0 = row0;
  gemm_norm_kernel<<<512 + 585, 256, 0, stream>>>(gp);
  row0 += 4680;
  // L5: sq1: E1 = f(E,Et) -> s2, dual E1t -> s4   (X3, q1t dead)
  for (int m = 0; m < 2; ++m)
    gp.jobs[m] = CJob{slot(m, 0), slot(m, 1), nullptr, slot(m, 2), slot(m, 4),
                      1.f};
  gp.row0 = row0;
  gemm_norm_kernel<<<512 + 585, 256, 0, stream>>>(gp);
  row0 += 4680;
  // L6: sq2: E2 = f(E1,E1t) -> s3, dual E2t -> s5   (X4 dead)
  for (int m = 0; m < 2; ++m)
    gp.jobs[m] = CJob{slot(m, 2), slot(m, 4), nullptr, slot(m, 3), slot(m, 5),
                      1.f};
  gp.row0 = row0;
  gemm_norm_kernel<<<512 + 585, 256, 0, stream>>>(gp);
  row0 += 4680;
  // L7: W = U^T = f(E2t_B, E2_A)
  gp.jobs[0] = CJob{slot(1, 5), slot(0, 3), nullptr, W, nullptr, 1.f};
  gp.njobs = 256; gp.row0 = row0;
  gemm_norm_kernel<<<256 + 586, 256, 0, stream>>>(gp);

  main_gemm_kernel<<<dim3(128, 4), 512, 0, stream>>>(Xn, W, bias, gate_out,
                                                     out);
}

// Round 15
// 204.709 us; speedup vs baseline: 1.1340x; 1.0137x over previous
//
#include <hip/hip_runtime.h>

// ---------------------------------------------------------------------------
// RefinedQuantumEntanglementLayer on MI355X (gfx950)
//
// out = (l2norm(x) @ expm(Mr-Mr^T) @ expm(Mi-Mi^T) + bias)^2 * softmax(qg)
//
// r15 (single change vs r14): main-GEMM block remap for L2 panel locality.
// Old bi-fastest order: ~32 concurrent blocks/XCD span 16 Xn panels (8MB)
// across two bj sweeps -> thrashes the 4MB XCD L2; each panel fetched 4x
// from L3. New mapping L -> (bj = (L/8)&3, bi = L%8 + 8*(L/32)): the 4
// bj-siblings of each bi are XCD-pinned (L%8 invariant) AND temporally
// adjacent -> concurrent set = 8 panels = 4MB = L2; each panel's 4 uses
// are simultaneous. Bijective, bit-exact (absmax must stay 3.576279e-07).
//
// Chain math (deg-8 Paterson-Stockmeyer, s=2, r14-verified):
//   X2 = -f(X,X); X3 = -f(X2,X); X4 = f(X2,X2)        [f(A,B) = A*B^T]
//   q0 = I+X+X2/2+X3/6 (f32); q1t = elementwise-transposed q1 (odd flips)
//   E  = f(X4,q1t)+q0 [dual-write -> Et]
//   squarings E1 = f(E,Et), E2 = f(E1,E1t) [duals E1t,E2t]
//   W = U^T = f(E2t_B, E2_A); main: out = f(Xn,W) epi (.+bias)^2*gate
// ---------------------------------------------------------------------------

typedef unsigned int u32;
typedef unsigned short u16;
typedef __attribute__((ext_vector_type(8))) short short8;   // 8 x bf16 raw
typedef __attribute__((ext_vector_type(4))) float f32x4;

#define GLOBAL_AS __attribute__((address_space(1)))
#define LDS_AS    __attribute__((address_space(3)))

constexpr int D = 1024;
constexpr float EXPM_SCALE = 1.0f / 4.0f;   // s = 2 squarings

__device__ __forceinline__ u16 f2bf(float f) {
  union { float f; u32 u; } v; v.f = f;
  u32 r = (v.u + 0x7FFFu + ((v.u >> 16) & 1u)) >> 16;
  return (u16)r;
}
__device__ __forceinline__ float bf2f(u16 u) {
  union { u32 u; float f; } v; v.u = ((u32)u) << 16;
  return v.f;
}

// async global->LDS, 16B per lane; lds base must be wave-uniform.
__device__ __forceinline__ void g2l16(const void* g, void* l) {
  __builtin_amdgcn_global_load_lds((const GLOBAL_AS u32*)g, (LDS_AS u32*)l,
                                   16, 0, 0);
}

#define WAITV(N)                                                   \
  do {                                                             \
    asm volatile("s_waitcnt vmcnt(" #N ")" ::: "memory");          \
    __builtin_amdgcn_sched_barrier(0);                             \
  } while (0)

// ---------------------------------------------------------------------------
// normalize 8 rows of x -> bf16 (tail body shared by chain launches)
__device__ void norm_rows8(const float* __restrict__ x, u16* __restrict__ Xn,
                           int r0, int tid, float* sred) {
  float4 v[8];
#pragma unroll
  for (int i = 0; i < 8; ++i)
    v[i] = ((const float4*)(x + (size_t)(r0 + i) * D))[tid];
  float ss[8];
#pragma unroll
  for (int i = 0; i < 8; ++i)
    ss[i] = v[i].x * v[i].x + v[i].y * v[i].y + v[i].z * v[i].z +
            v[i].w * v[i].w;
  for (int o = 32; o; o >>= 1)
#pragma unroll
    for (int i = 0; i < 8; ++i) ss[i] += __shfl_down(ss[i], o);
  const int w = tid >> 6;
  if ((tid & 63) == 0)
#pragma unroll
    for (int i = 0; i < 8; ++i) sred[i * 4 + w] = ss[i];
  __syncthreads();
#pragma unroll
  for (int i = 0; i < 8; ++i) {
    const float tot =
        sred[i * 4 + 0] + sred[i * 4 + 1] + sred[i * 4 + 2] + sred[i * 4 + 3];
    const float inv = rsqrtf(fmaxf(tot, 1e-12f));
    ushort4 o4;
    o4.x = f2bf(v[i].x * inv); o4.y = f2bf(v[i].y * inv);
    o4.z = f2bf(v[i].z * inv); o4.w = f2bf(v[i].w * inv);
    ((ushort4*)(Xn + (size_t)(r0 + i) * D))[tid] = o4;
  }
}

// ---------------------------------------------------------------------------
// L1: skew tiles (512 jobs) + norm tail
struct SkewParams {
  const float *Mr, *Mi;
  u16 *X0, *X1;
  const float* x;
  u16* Xn;
  int row0;
};
__global__ __launch_bounds__(256) void skew_norm_kernel(SkewParams p) {
  __shared__ __align__(16) float t2[64][67];
  const int bid = blockIdx.x, tid = threadIdx.x;
  if (bid >= 512) {
    norm_rows8(p.x, p.Xn, p.row0 + (bid - 512) * 8, tid, &t2[0][0]);
    return;
  }
  const int z = bid >> 8, t = bid & 255;
  const float* M = z ? p.Mi : p.Mr;
  u16* X = z ? p.X1 : p.X0;
  const int bi = t >> 4, bj = t & 15;
  const int r0 = tid >> 4, c0 = (tid & 15) * 4;
  float4 own[4];
#pragma unroll
  for (int i = 0; i < 4; ++i) {
    const int r = i * 16 + r0;
    own[i] = *(const float4*)(M + (size_t)(bi * 64 + r) * D + bj * 64 + c0);
    const float4 tr =
        *(const float4*)(M + (size_t)(bj * 64 + r) * D + bi * 64 + c0);
    t2[r][c0 + 0] = tr.x; t2[r][c0 + 1] = tr.y;
    t2[r][c0 + 2] = tr.z; t2[r][c0 + 3] = tr.w;
  }
  __syncthreads();
#pragma unroll
  for (int i = 0; i < 4; ++i) {
    const int r = i * 16 + r0;
    const float o[4] = {own[i].x, own[i].y, own[i].z, own[i].w};
    ushort4 hv;
    u16* hp = (u16*)&hv;
#pragma unroll
    for (int j = 0; j < 4; ++j)
      hp[j] = f2bf((o[j] - t2[c0 + j][r]) * EXPM_SCALE);
    *(ushort4*)(X + (size_t)(bi * 64 + r) * D + bj * 64 + c0) = hv;
  }
}

// ---------------------------------------------------------------------------
// generic chain GEMM round + norm tail (r12 body). 64x64 tile, BK=64,
// 4 waves (2x2, 32x32 each), 3 LDS bufs (48KB -> 3 blocks/CU), 2-ahead
// prefetch, counted vmcnt(4), tail 4/0.
struct CJob {
  const u16 *A, *B;
  const float* C;
  u16 *Dst, *DT;
  float alpha;
};
struct GNParams {
  CJob jobs[2];
  int njobs;
  const float* x;
  u16* Xn;
  int row0;
};
__global__ __launch_bounds__(256) void gemm_norm_kernel(GNParams p) {
  __shared__ __align__(16) u16 ldsA[3][4096];
  __shared__ __align__(16) u16 ldsB[3][4096];
  const int bid = blockIdx.x, tid = threadIdx.x;
  if (bid >= p.njobs) {
    norm_rows8(p.x, p.Xn, p.row0 + (bid - p.njobs) * 8, tid,
               (float*)&ldsA[0][0]);
    return;
  }
  const CJob jb = p.jobs[bid >> 8];
  const int bi = (bid >> 4) & 15, bj = bid & 15;
  const int w = tid >> 6, lane = tid & 63;
  const int wr = w >> 1, wc = w & 1;
  f32x4 acc[2][2];
#pragma unroll
  for (int m = 0; m < 2; ++m)
#pragma unroll
    for (int n = 0; n < 2; ++n) acc[m][n] = f32x4{0.f, 0.f, 0.f, 0.f};
  const int r_l = lane >> 3, c_l = lane & 7;

  auto stage = [&](int buf, int kt) {   // 4 g2l16 per thread
    const int k0 = kt * 64;
#pragma unroll
    for (int pp = 0; pp < 2; ++pp) {
      const int row = pp * 32 + w * 8 + r_l;
      const int chunk = c_l ^ (row & 7);  // inverse swizzle on global source
      g2l16(jb.A + (size_t)(bi * 64 + row) * D + k0 + chunk * 8,
            (char*)&ldsA[buf][0] + pp * 4096 + w * 1024);
      g2l16(jb.B + (size_t)(bj * 64 + row) * D + k0 + chunk * 8,
            (char*)&ldsB[buf][0] + pp * 4096 + w * 1024);
    }
  };
  auto compute = [&](int buf) {
#pragma unroll
    for (int h = 0; h < 2; ++h) {
      const int kk = h * 32 + (lane >> 4) * 8;
      short8 a[2], b[2];
#pragma unroll
      for (int m = 0; m < 2; ++m) {
        const int row = wr * 32 + m * 16 + (lane & 15);
        const int off = row * 128 + ((kk * 2) ^ ((row & 7) << 4));
        a[m] = *(const short8*)((const char*)&ldsA[buf][0] + off);
      }
#pragma unroll
      for (int n = 0; n < 2; ++n) {
        const int row = wc * 32 + n * 16 + (lane & 15);
        const int off = row * 128 + ((kk * 2) ^ ((row & 7) << 4));
        b[n] = *(const short8*)((const char*)&ldsB[buf][0] + off);
      }
#pragma unroll
      for (int m = 0; m < 2; ++m)
#pragma unroll
        for (int n = 0; n < 2; ++n)
          acc[m][n] = __builtin_amdgcn_mfma_f32_16x16x32_bf16(
              a[m], b[n], acc[m][n], 0, 0, 0);
    }
  };

  stage(0, 0); stage(1, 1);   // 8 loads in flight (2-ahead)
  for (int s = 0; s < 14; ++s) {
    WAITV(4);                         // own G(s) landed (G(s+1) may fly)
    __builtin_amdgcn_s_barrier();     // all threads' G(s) landed;
    __builtin_amdgcn_sched_barrier(0);//  all threads finished compute(s-1)
    stage((s + 2) % 3, s + 2);        // overwrites buf(s-1): reads done
    compute(s % 3);
  }
  WAITV(4);
  __builtin_amdgcn_s_barrier();
  __builtin_amdgcn_sched_barrier(0);
  compute(14 % 3);
  WAITV(0);
  __builtin_amdgcn_s_barrier();
  __builtin_amdgcn_sched_barrier(0);
  compute(15 % 3);

  const int or0 = bi * 64 + wr * 32, oc0 = bj * 64 + wc * 32;
#pragma unroll
  for (int m = 0; m < 2; ++m)
#pragma unroll
    for (int n = 0; n < 2; ++n) {
      const int row0 = or0 + m * 16 + (lane >> 4) * 4;
      const int col = oc0 + n * 16 + (lane & 15);
      ushort4 dv;
      u16* dp = (u16*)&dv;
#pragma unroll
      for (int r = 0; r < 4; ++r) {
        float v = acc[m][n][r] * jb.alpha;
        if (jb.C) v += jb.C[(size_t)(row0 + r) * D + col];
        dp[r] = f2bf(v);
        jb.Dst[(size_t)(row0 + r) * D + col] = dp[r];
      }
      if (jb.DT)  // transposed tile: DT[col][row0..row0+3], one 8B store
        *(ushort4*)(jb.DT + (size_t)col * D + row0) = dv;
    }
}

// ---------------------------------------------------------------------------
// L3: fused X3/X4 + buildq + gate + norm tail (r12 body). BK=32, 3 arrays
// x 3 bufs x 4KB = 36KB (4 blocks/CU), 2-ahead, counted vmcnt(3), tail 3/0.
struct X34Params {
  const u16 *X[2], *X2[2];
  u16 *X3[2], *X4[2], *q1t[2];
  float* q0[2];
  const float* qg;
  float* gate_out;
  const float* x;
  u16* Xn;
  int row0;
};
__global__ __launch_bounds__(256) void x34q_norm_kernel(X34Params p) {
  __shared__ __align__(16) u16 ldsA[3][2048];
  __shared__ __align__(16) u16 ldsB1[3][2048];
  __shared__ __align__(16) u16 ldsB2[3][2048];
  const int bid = blockIdx.x, tid = threadIdx.x;
  if (bid > 512) {
    norm_rows8(p.x, p.Xn, p.row0 + (bid - 513) * 8, tid, (float*)&ldsA[0][0]);
    return;
  }
  if (bid == 512) {  // gate softmax
    float* red = (float*)&ldsA[0][0];
    const float4 v = ((const float4*)p.qg)[tid];
    float mx = fmaxf(fmaxf(v.x, v.y), fmaxf(v.z, v.w));
    for (int o = 32; o; o >>= 1) mx = fmaxf(mx, __shfl_xor(mx, o));
    if ((tid & 63) == 0) red[tid >> 6] = mx;
    __syncthreads();
    const float M = fmaxf(fmaxf(red[0], red[1]), fmaxf(red[2], red[3]));
    __syncthreads();
    const float e0 = __expf(v.x - M), e1 = __expf(v.y - M),
                e2 = __expf(v.z - M), e3 = __expf(v.w - M);
    float s = e0 + e1 + e2 + e3;
    for (int o = 32; o; o >>= 1) s += __shfl_xor(s, o);
    if ((tid & 63) == 0) red[tid >> 6] = s;
    __syncthreads();
    const float S = red[0] + red[1] + red[2] + red[3];
    const float4 o4 = {e0 / S, e1 / S, e2 / S, e3 / S};
    ((float4*)p.gate_out)[tid] = o4;
    return;
  }
  const int mz = bid >> 8, t = bid & 255;
  const int bi = t >> 4, bj = t & 15;
  const u16* Ag = p.X2[mz];
  const u16* B1g = p.X[mz];
  const u16* B2g = p.X2[mz];
  const int w = tid >> 6, lane = tid & 63;
  const int wr = w >> 1, wc = w & 1;
  f32x4 acc3[2][2], acc4[2][2];
#pragma unroll
  for (int m = 0; m < 2; ++m)
#pragma unroll
    for (int n = 0; n < 2; ++n) {
      acc3[m][n] = f32x4{0.f, 0.f, 0.f, 0.f};
      acc4[m][n] = f32x4{0.f, 0.f, 0.f, 0.f};
    }
  const int srow = tid >> 2, sc = tid & 3;   // stage: row 0..63, chunk 0..3

  auto stage = [&](int buf, int s) {   // 3 g2l16 per thread (one per array)
    const int k0 = s * 32;
    const int csrc = sc ^ (srow & 3);  // inverse swizzle on global source
    g2l16(Ag + (size_t)(bi * 64 + srow) * D + k0 + csrc * 8,
          (char*)&ldsA[buf][0] + tid * 16);
    g2l16(B1g + (size_t)(bj * 64 + srow) * D + k0 + csrc * 8,
          (char*)&ldsB1[buf][0] + tid * 16);
    g2l16(B2g + (size_t)(bj * 64 + srow) * D + k0 + csrc * 8,
          (char*)&ldsB2[buf][0] + tid * 16);
  };
  const int h4 = lane >> 4;  // 8-elem chunk within the 32-wide K step
  auto compute = [&](int buf) {
    short8 a[2], b1[2], b2[2];
#pragma unroll
    for (int m = 0; m < 2; ++m) {
      const int row = wr * 32 + m * 16 + (lane & 15);
      const int off = row * 64 + ((h4 ^ (row & 3)) << 4);
      a[m] = *(const short8*)((const char*)&ldsA[buf][0] + off);
    }
#pragma unroll
    for (int n = 0; n < 2; ++n) {
      const int row = wc * 32 + n * 16 + (lane & 15);
      const int off = row * 64 + ((h4 ^ (row & 3)) << 4);
      b1[n] = *(const short8*)((const char*)&ldsB1[buf][0] + off);
      b2[n] = *(const short8*)((const char*)&ldsB2[buf][0] + off);
    }
#pragma unroll
    for (int m = 0; m < 2; ++m)
#pragma unroll
      for (int n = 0; n < 2; ++n) {
        acc3[m][n] = __builtin_amdgcn_mfma_f32_16x16x32_bf16(
            a[m], b1[n], acc3[m][n], 0, 0, 0);
        acc4[m][n] = __builtin_amdgcn_mfma_f32_16x16x32_bf16(
            a[m], b2[n], acc4[m][n], 0, 0, 0);
      }
  };

  stage(0, 0); stage(1, 1);   // 6 loads in flight (2-ahead)
  for (int s = 0; s < 30; ++s) {
    WAITV(3);                          // own G(s) landed
    __builtin_amdgcn_s_barrier();
    __builtin_amdgcn_sched_barrier(0);
    stage((s + 2) % 3, s + 2);         // overwrites buf(s-1): reads done
    compute(s % 3);
  }
  WAITV(3);
  __builtin_amdgcn_s_barrier();
  __builtin_amdgcn_sched_barrier(0);
  compute(30 % 3);
  WAITV(0);
  __builtin_amdgcn_s_barrier();
  __builtin_amdgcn_sched_barrier(0);
  compute(31 % 3);

  const int or0 = bi * 64 + wr * 32, oc0 = bj * 64 + wc * 32;
#pragma unroll
  for (int m = 0; m < 2; ++m)
#pragma unroll
    for (int n = 0; n < 2; ++n) {
      const int row0 = or0 + m * 16 + (lane >> 4) * 4;
      const int col = oc0 + n * 16 + (lane & 15);
#pragma unroll
      for (int r = 0; r < 4; ++r) {
        const size_t idx = (size_t)(row0 + r) * D + col;
        const u16 x3v = f2bf(-acc3[m][n][r]);
        const u16 x4v = f2bf(acc4[m][n][r]);
        p.X3[mz][idx] = x3v;
        p.X4[mz][idx] = x4v;
        const float d = (row0 + r == col) ? 1.f : 0.f;
        const float xf = bf2f(p.X[mz][idx]);
        const float x2f = bf2f(p.X2[mz][idx]);
        const float x3f = bf2f(x3v), x4f = bf2f(x4v);
        p.q0[mz][idx] = d + xf + x2f * 0.5f + x3f * (1.f / 6.f);
        p.q1t[mz][idx] =
            f2bf(d * (1.f / 24.f) - xf * (1.f / 120.f) + x2f * (1.f / 720.f) -
                 x3f * (1.f / 5040.f) + x4f * (1.f / 40320.f));
      }
    }
}

// ---------------------------------------------------------------------------
// main GEMM (r10/r12 pipeline; r15: XCD-pinned, bj-adjacent block remap).
// L = linear block id; bj = (L/8)&3, bi = L%8 + 8*(L/32). The 4 bj-siblings
// of each bi share L%8 (same XCD under round-robin) and are temporally
// adjacent -> concurrent set per XCD = 8 Xn panels = 4MB = L2.
// out[r][c] = (f(Xn,W) + bias[c])^2 * gate[c]
// 256x256 tile, BK=32, 8 waves (2x4), 4 LDS bufs (128 KiB), 3-ahead
// prefetch, counted vmcnt(8) before raw s_barrier (no full drains).
__global__ __launch_bounds__(512, 1) void main_gemm_kernel(
    const u16* __restrict__ Xn, const u16* __restrict__ Wm,
    const float* __restrict__ bias, const float* __restrict__ gate,
    float* __restrict__ out) {
  const int tid = threadIdx.x;
  const int wid = tid >> 6, lane = tid & 63;
  const int wr = wid >> 2, wc = wid & 3;   // 2 x 4 waves
  __shared__ u16 lds[4 * 16384];           // 4 bufs x (A 16KB + B 16KB)
  f32x4 acc[8][4];
#pragma unroll
  for (int m = 0; m < 8; ++m)
#pragma unroll
    for (int n = 0; n < 4; ++n) acc[m][n] = f32x4{0.f, 0.f, 0.f, 0.f};

  const int L = blockIdx.x;                 // 512 blocks, 1D
  const int bj = (L >> 3) & 3;              // 0..3
  const int bi = (L & 7) + 8 * (L >> 5);    // 0..127
  const int r_ = tid >> 2;   // 0..127
  const int c_ = tid & 3;

  auto stage = [&](int s) {
    char* base = (char*)lds + (s & 3) * 32768;
#pragma unroll
    for (int pp = 0; pp < 2; ++pp) {
      const int row = pp * 128 + r_;
      const int csrc = c_ ^ ((row >> 1) & 3);  // inverse swizzle on source
      g2l16(Xn + (size_t)(bi * 256 + row) * D + s * 32 + csrc * 8,
            base + pp * 8192 + tid * 16);
      g2l16(Wm + (size_t)(bj * 256 + row) * D + s * 32 + csrc * 8,
            base + 16384 + pp * 8192 + tid * 16);
    }
  };

  const int h = lane >> 4;  // k-chunk 0..3 within 32-wide step
  auto compute = [&](int s) {
    const char* base = (const char*)lds + (s & 3) * 32768;
    short8 a[8], b[4];
#pragma unroll
    for (int m = 0; m < 8; ++m) {
      const int row = wr * 128 + m * 16 + (lane & 15);
      const int off = row * 64 + ((h ^ ((row >> 1) & 3)) << 4);
      a[m] = *(const short8*)(base + off);
    }
#pragma unroll
    for (int n = 0; n < 4; ++n) {
      const int row = wc * 64 + n * 16 + (lane & 15);
      const int off = 16384 + row * 64 + ((h ^ ((row >> 1) & 3)) << 4);
      b[n] = *(const short8*)(base + off);
    }
    __builtin_amdgcn_s_setprio(1);
#pragma unroll
    for (int m = 0; m < 8; ++m)
#pragma unroll
      for (int n = 0; n < 4; ++n)
        acc[m][n] = __builtin_amdgcn_mfma_f32_16x16x32_bf16(a[m], b[n],
                                                            acc[m][n], 0, 0, 0);
    __builtin_amdgcn_s_setprio(0);
  };

  stage(0); stage(1); stage(2);   // 12 loads in flight
  for (int s = 0; s < 29; ++s) {
    WAITV(8);
    __builtin_amdgcn_s_barrier();
    __builtin_amdgcn_sched_barrier(0);
    stage(s + 3);
    compute(s);
  }
  WAITV(8);
  __builtin_amdgcn_s_barrier();
  __builtin_amdgcn_sched_barrier(0);
  compute(29);
  WAITV(4);
  __builtin_amdgcn_s_barrier();
  __builtin_amdgcn_sched_barrier(0);
  compute(30);
  WAITV(0);
  __builtin_amdgcn_s_barrier();
  __builtin_amdgcn_sched_barrier(0);
  compute(31);

  const int or0 = bi * 256 + wr * 128, oc0 = bj * 256 + wc * 64;
#pragma unroll
  for (int m = 0; m < 8; ++m)
#pragma unroll
    for (int n = 0; n < 4; ++n) {
      const int col = oc0 + n * 16 + (lane & 15);
      const float bc = bias[col], gc = gate[col];
#pragma unroll
      for (int r = 0; r < 4; ++r) {
        const int row = or0 + m * 16 + (lane >> 4) * 4 + r;
        const float t = acc[m][n][r] + bc;
        out[(size_t)row * D + col] = t * t * gc;
      }
    }
}

// ---------------------------------------------------------------------------
extern "C" void kernel_launch(void* const* d_in, const int* in_sizes, int n_in,
                              void* d_out, int out_size, void* d_ws,
                              size_t ws_size, hipStream_t stream) {
  (void)in_sizes; (void)n_in; (void)out_size; (void)ws_size;
  const float* inp = (const float*)d_in[0];
  const float* Mr = (const float*)d_in[1];
  const float* Mi = (const float*)d_in[2];
  const float* bias = (const float*)d_in[3];
  const float* qg = (const float*)d_in[4];
  float* out = (float*)d_out;
  float* gate_out = out + (size_t)32768 * 1024;

  char* ws = (char*)d_ws;
  u16* Xn = (u16*)ws;  // 64 MB
  // per-matrix region (16 MB): 6 bf16 slots (2 MB) + q0 (4 MB f32).
  // lifetimes (s=2): s0 X->E, s1 X2->Et, s2 X3->E1, s3 X4->E2,
  //                  s4 q1t->E1t, s5 E2t
  auto slot = [&](int m, int s) -> u16* {
    return (u16*)(ws + 67108864 + (size_t)m * 16777216 + (size_t)s * 2097152);
  };
  auto q0p = [&](int m) -> float* {
    return (float*)(ws + 67108864 + (size_t)m * 16777216 + 12582912);
  };
  u16* W = (u16*)(ws + 100663296);  // 96 MB: 2 MB

  // normalize rows spread over the 7 chain launches:
  // L1-L6: 585 blocks x 8 rows = 4680 each; L7: 586 blocks = 4688.
  int row0 = 0;

  // L1: skew
  {
    SkewParams sp{Mr, Mi, slot(0, 0), slot(1, 0), inp, Xn, row0};
    skew_norm_kernel<<<512 + 585, 256, 0, stream>>>(sp);
    row0 += 4680;
  }
  GNParams gp{};
  gp.x = inp; gp.Xn = Xn;
  // L2: X2 = -f(X,X) -> s1
  for (int m = 0; m < 2; ++m)
    gp.jobs[m] = CJob{slot(m, 0), slot(m, 0), nullptr, slot(m, 1), nullptr,
                      -1.f};
  gp.njobs = 512; gp.row0 = row0;
  gemm_norm_kernel<<<512 + 585, 256, 0, stream>>>(gp);
  row0 += 4680;
  // L3: fused X3/X4 + buildq + gate
  {
    X34Params xp{};
    for (int m = 0; m < 2; ++m) {
      xp.X[m] = slot(m, 0); xp.X2[m] = slot(m, 1);
      xp.X3[m] = slot(m, 2); xp.X4[m] = slot(m, 3);
      xp.q1t[m] = slot(m, 4); xp.q0[m] = q0p(m);
    }
    xp.qg = qg; xp.gate_out = gate_out;
    xp.x = inp; xp.Xn = Xn; xp.row0 = row0;
    x34q_norm_kernel<<<513 + 585, 256, 0, stream>>>(xp);
    row0 += 4680;
  }
  // L4: E = f(X4, q1t) + q0 -> s0, dual Et -> s1   (X, X2 dead)
  for (int m = 0; m < 2; ++m)
    gp.jobs[m] = CJob{slot(m, 3), slot(m, 4), q0p(m), slot(m, 0), slot(m, 1),
                      1.f};
  gp.njobs = 512; gp.row0 = row0;
  gemm_norm_kernel<<<512 + 585, 256, 0, stream>>>(gp);
  row0 += 4680;
  // L5: sq1: E1 = f(E,Et) -> s2, dual E1t -> s4   (X3, q1t dead)
  for (int m = 0; m < 2; ++m)
    gp.jobs[m] = CJob{slot(m, 0), slot(m, 1), nullptr, slot(m, 2), slot(m, 4),
                      1.f};
  gp.row0 = row0;
  gemm_norm_kernel<<<512 + 585, 256, 0, stream>>>(gp);
  row0 += 4680;
  // L6: sq2: E2 = f(E1,E1t) -> s3, dual E2t -> s5   (X4 dead)
  for (int m = 0; m < 2; ++m)
    gp.jobs[m] = CJob{slot(m, 2), slot(m, 4), nullptr, slot(m, 3), slot(m, 5),
                      1.f};
  gp.row0 = row0;
  gemm_norm_kernel<<<512 + 585, 256, 0, stream>>>(gp);
  row0 += 4680;
  // L7: W = U^T = f(E2t_B, E2_A)
  gp.jobs[0] = CJob{slot(1, 5), slot(0, 3), nullptr, W, nullptr, 1.f};
  gp.njobs = 256; gp.row0 = row0;
  gemm_norm_kernel<<<256 + 586, 256, 0, stream>>>(gp);

  main_gemm_kernel<<<512, 512, 0, stream>>>(Xn, W, bias, gate_out, out);
}